// Round 6
// baseline (146.124 us; speedup 1.0000x reference)
//
#include <hip/hip_runtime.h>

#define K_KNOTS 1024
#define N_CTRL  1021
#define TABM    2048            // buckets for the {t1,s0} jump table (16 KB)
#define MGRID   4096            // tref quantization grid packed into coef.w

typedef float vfloat4 __attribute__((ext_vector_type(4)));   // nontemporal-safe

struct __align__(8) TabE { float t1; unsigned int s0; };     // one dwordx2

// ---------------------------------------------------------------------------
// Kernel 1: rank sort of the 1024 knots (stable, tie-safe).
// 16 blocks x 256: block owns 64 elements; wave q (=tid>>6) scans knot
// quarter q for all 64 elements -> partial ranks; 4-way LDS reduction.
// (History: 1-wave-per-block original cost ~20+ us serial; cooperative
// sort+prep fusion REGRESSED +26 us (graph-capture-hostile); prep fused
// into eval prologue REGRESSED +5 us (redundant per-block work x1024).
// Plain small kernels, work done once, is the optimum for this harness.)
// ---------------------------------------------------------------------------
__global__ __launch_bounds__(256) void sort_knots_kernel(
        const float* __restrict__ knots, float* __restrict__ ts) {
    __shared__ __align__(16) float kl[K_KNOTS];
    __shared__ int part[4][64];
    const int tid  = threadIdx.x;
    const int lane = tid & 63;          // element slot within the block
    const int q    = tid >> 6;          // knot quarter (uniform per wave)
    const int e    = blockIdx.x * 64 + lane;   // global element index

    ((float4*)kl)[tid] = ((const float4*)knots)[tid];   // 256 x float4 = 1024
    __syncthreads();

    const float my = kl[e];
    int rank = 0;
    const float4* kl4 = (const float4*)kl;
    const int j4lo = q * (K_KNOTS / 16);       // 64 float4 per quarter
#pragma unroll 8
    for (int j4 = j4lo; j4 < j4lo + K_KNOTS / 16; ++j4) {
        const float4 v = kl4[j4];              // broadcast (uniform per wave)
        const int j = j4 * 4;
        rank += (v.x < my || (v.x == my && j + 0 < e)) ? 1 : 0;
        rank += (v.y < my || (v.y == my && j + 1 < e)) ? 1 : 0;
        rank += (v.z < my || (v.z == my && j + 2 < e)) ? 1 : 0;
        rank += (v.w < my || (v.w == my && j + 3 < e)) ? 1 : 0;
    }
    part[q][lane] = rank;
    __syncthreads();
    if (q == 0) {
        const int r = part[0][lane] + part[1][lane] + part[2][lane] + part[3][lane];
        ts[r] = my;
    }
}

// ---------------------------------------------------------------------------
// Cubic in u = x - tref carried through the de Boor recursion (prep only,
// double precision to kill cancellation for tiny knot gaps).
// ---------------------------------------------------------------------------
struct PolyD { double c0, c1, c2, c3; };

__device__ __forceinline__ PolyD lerp_poly(const PolyD dl, const PolyD dr,
                                           double tl, double tr, double tref) {
    const double inv = 1.0 / (tr - tl);
    const double A = (tref - tl) * inv;
    const double e0 = dr.c0 - dl.c0, e1 = dr.c1 - dl.c1;
    const double e2 = dr.c2 - dl.c2, e3 = dr.c3 - dl.c3;
    PolyD o;
    o.c0 = dl.c0 + A * e0;
    o.c1 = dl.c1 + A * e1 + inv * e0;
    o.c2 = dl.c2 + A * e2 + inv * e1;
    o.c3 = dl.c3 + A * e3 + inv * e2;
    return o;
}

// cubic for interval s (ts[s-1] < x <= ts[s], s in [4,1020]) centered at tref
__device__ __forceinline__ float4 interval_poly(const float* tss,
                                                const float* __restrict__ c,
                                                int s, double tref) {
    const double T0 = tss[s - 3], T1 = tss[s - 2], T2 = tss[s - 1];
    const double T3 = tss[s],     T4 = tss[s + 1], T5 = tss[s + 2];
    PolyD d0 = {(double)c[s - 4], 0, 0, 0}, d1 = {(double)c[s - 3], 0, 0, 0};
    PolyD d2 = {(double)c[s - 2], 0, 0, 0}, d3 = {(double)c[s - 1], 0, 0, 0};
    d3 = lerp_poly(d2, d3, T2, T5, tref);   // r=1
    d2 = lerp_poly(d1, d2, T1, T4, tref);
    d1 = lerp_poly(d0, d1, T0, T3, tref);
    d3 = lerp_poly(d2, d3, T2, T4, tref);   // r=2
    d2 = lerp_poly(d1, d2, T1, T3, tref);
    d3 = lerp_poly(d2, d3, T2, T3, tref);   // r=3
    return make_float4((float)d3.c0, (float)d3.c1, (float)d3.c2, (float)d3.c3);
}

// ---------------------------------------------------------------------------
// Kernel 2 (prep), 12 blocks x 256:
//  threads 0..1023    -> coef[s]: interval cubic centered at gm = m/MGRID,
//                        m = round(ts[s]*MGRID); m packed into the low 13
//                        mantissa bits of c3 (<=2^-10 rel perturbation).
//  threads 1024..3071 -> tab[b] = {t1 = ts[s0], s0} where s0 = clamp(
//                        lower_bound(ts, Lb-eps), 4, 1020). First scan
//                        iteration precomputed; eval does s = s0 + (t1<x),
//                        then a check read + rare scan.
// ---------------------------------------------------------------------------
__device__ __forceinline__ int lower_bound_s(const float* tss, float v) {
    int lo = 0, hi = K_KNOTS;
    while (lo < hi) {
        const int mid = (lo + hi) >> 1;
        if (tss[mid] < v) lo = mid + 1; else hi = mid;
    }
    return lo;
}

__global__ void prep_kernel(const float* __restrict__ ts,
                            const float* __restrict__ c,
                            float4* __restrict__ coefI,
                            TabE* __restrict__ tab) {
    __shared__ float tss[K_KNOTS];
    const int tid = threadIdx.x;
    for (int i = tid; i < K_KNOTS; i += blockDim.x) tss[i] = ts[i];
    __syncthreads();

    const int g = blockIdx.x * blockDim.x + tid;   // 0..3071
    if (g < K_KNOTS) {
        const int s = g;
        float4 out = make_float4(0.f, 0.f, 0.f, 0.f);
        if (s >= 4 && s <= 1020) {
            int m = (int)((double)tss[s] * (double)MGRID + 0.5);
            m = m < 0 ? 0 : (m > MGRID ? MGRID : m);         // fits 13 bits
            const double gm = (double)m * (1.0 / (double)MGRID);
            float4 p = interval_poly(tss, c, s, gm);
            const unsigned int wb =
                (__float_as_uint(p.w) & ~0x1FFFu) | (unsigned int)m;
            p.w = __uint_as_float(wb);
            out = p;
        }
        coefI[s] = out;
    } else {
        const int b = g - K_KNOTS;                 // 0..2047
        const float eps = 1e-6f;                   // >> 6e-8 edge-rounding slack
        const float Lb = (float)b * (1.0f / (float)TABM) - eps;
        int s0 = lower_bound_s(tss, Lb);
        // clamp: domain guarantees true s in [4,1020] and s0 <= true s, so
        // clamping keeps s0 <= true s for every queried bucket (scan fixes up)
        s0 = s0 < 4 ? 4 : (s0 > 1020 ? 1020 : s0);
        TabE e; e.t1 = tss[s0]; e.s0 = (unsigned int)s0;
        tab[b] = e;
    }
}

// ---------------------------------------------------------------------------
// Kernel 3: evaluation. R5 counters: 41.6us, 2.4TB/s (30% peak), VALU 35%,
// occ ~31% -> LATENCY-bound at 16 waves/CU, not pipe-bound. Round-6 levers:
//  * tab gather moved LDS -> global (L1-resident 16 KB, read-only, hot):
//    frees 16 KB LDS and offloads the LDS pipe.
//  * ts pad dropped (provably unreachable: x < ts[1020] stops every scan at
//    s <= 1020, and ss = s0+(t1<x) <= 1020 since t1=ts[1020] > x).
//    LDS = coef 16K + ts 4K = 20 KB exactly -> 8 blocks/CU = 32 waves (2x).
//  * explicit x-prefetch pipeline: next iteration's 2 vfloat4 issued before
//    processing current -> x-load latency off the dependent chain.
// Math bit-identical to R2-R5 main loop.
// ---------------------------------------------------------------------------
__global__ __launch_bounds__(256, 8) void eval_kernel(
        const vfloat4* __restrict__ x4,
        const float* __restrict__ ts_g,
        const float4* __restrict__ coefI_g,
        const TabE* __restrict__ tab_g,
        vfloat4* __restrict__ out4, int n4) {
    __shared__ __align__(16) float4 coefI_s[K_KNOTS]; // 16 KB
    __shared__ __align__(16) float  ts_s[K_KNOTS];    // 4 KB  (20 KB total)
    const int tid = threadIdx.x;

#pragma unroll
    for (int i = tid; i < K_KNOTS; i += 256) coefI_s[i] = coefI_g[i];
    ((float4*)ts_s)[tid] = ((const float4*)ts_g)[tid];   // 256 x float4
    __syncthreads();

    const int gid    = blockIdx.x * 256 + tid;
    const int stride = gridDim.x * 256;

    int i = gid;
    if (i >= n4) return;
    // prologue loads
    vfloat4 xa = __builtin_nontemporal_load(&x4[i]);
    bool has2 = (i + stride) < n4;
    vfloat4 xb = has2 ? __builtin_nontemporal_load(&x4[i + stride]) : xa;

    while (true) {
        const int inext = i + 2 * stride;
        // prefetch next pair before processing current (latency off-chain)
        vfloat4 xa_n = xa, xb_n = xb;
        bool hasn = inext < n4, has2n = false;
        if (hasn) {
            xa_n  = __builtin_nontemporal_load(&x4[inext]);
            has2n = (inext + stride) < n4;
            xb_n  = has2n ? __builtin_nontemporal_load(&x4[inext + stride]) : xa_n;
        }

        float xx[8] = {xa.x, xa.y, xa.z, xa.w, xb.x, xb.y, xb.z, xb.w};

        // P1: fused table+probe1 (8 independent global dwordx2, L1-resident)
        TabE eb[8];
#pragma unroll
        for (int j = 0; j < 8; ++j) {
            const int b = (int)(xx[j] * (float)TABM);
            eb[j] = tab_g[b];
        }
        // P2: increment + loop-entry check read (8 independent ds_read_b32)
        int ss[8];
#pragma unroll
        for (int j = 0; j < 8; ++j)
            ss[j] = (int)eb[j].s0 + ((eb[j].t1 < xx[j]) ? 1 : 0);
        float tt[8];
#pragma unroll
        for (int j = 0; j < 8; ++j) tt[j] = ts_s[ss[j]];
        // P3: rare residual scan (exact lower bound from any start <= true s;
        // terminates at s <= 1020 because ts[1020] > x over the whole domain)
#pragma unroll
        for (int j = 0; j < 8; ++j) {
            while (tt[j] < xx[j]) { ++ss[j]; tt[j] = ts_s[ss[j]]; }
        }
        // P4: coefficient fetch (8 independent ds_read_b128) + Horner
        float4 ee[8];
#pragma unroll
        for (int j = 0; j < 8; ++j) ee[j] = coefI_s[ss[j]];
        float rr[8];
#pragma unroll
        for (int j = 0; j < 8; ++j) {
            const float4 e = ee[j];
            const int m = (int)(__float_as_uint(e.w) & 0x1FFFu);
            const float u = __builtin_fmaf((float)m, -1.0f / (float)MGRID, xx[j]);
            rr[j] = e.x + u * (e.y + u * (e.z + u * e.w));
        }
        vfloat4 ra, rb;
        ra.x = rr[0]; ra.y = rr[1]; ra.z = rr[2]; ra.w = rr[3];
        rb.x = rr[4]; rb.y = rr[5]; rb.z = rr[6]; rb.w = rr[7];
        __builtin_nontemporal_store(ra, &out4[i]);
        if (has2) __builtin_nontemporal_store(rb, &out4[i + stride]);

        if (!hasn) break;
        i = inext; xa = xa_n; xb = xb_n; has2 = has2n;
    }
}

extern "C" void kernel_launch(void* const* d_in, const int* in_sizes, int n_in,
                              void* d_out, int out_size, void* d_ws, size_t ws_size,
                              hipStream_t stream) {
    const float* x     = (const float*)d_in[0];  // [16777216]
    const float* knots = (const float*)d_in[1];  // [1024] unsorted
    const float* c     = (const float*)d_in[2];  // [1021]
    float* out = (float*)d_out;

    // ws layout: ts @0 (4 KB) | coefI @4K (16 KB) | tab @20K (16 KB)
    float*  ts_ws    = (float*)d_ws;
    float4* coefI_ws = (float4*)((char*)d_ws + 4096);
    TabE*   tab_ws   = (TabE*)((char*)d_ws + 4096 + 16384);

    sort_knots_kernel<<<16, 256, 0, stream>>>(knots, ts_ws);
    prep_kernel<<<(K_KNOTS + TABM) / 256, 256, 0, stream>>>(ts_ws, c, coefI_ws, tab_ws);

    const int n4 = out_size / 4;   // 4,194,304
    // 2048 blocks = 8 resident blocks/CU x 256 CUs (20 KB LDS -> 8 blocks/CU)
    eval_kernel<<<2048, 256, 0, stream>>>((const vfloat4*)x, ts_ws, coefI_ws,
                                          tab_ws, (vfloat4*)out, n4);
}

// Round 7
// 136.277 us; speedup vs baseline: 1.0723x; 1.0723x over previous
//
#include <hip/hip_runtime.h>

#define K_KNOTS 1024
#define N_CTRL  1021
#define TABM    2048            // buckets for the {t1,s0} jump table (16 KB)
#define MGRID   4096            // tref quantization grid packed into coef.w
#define TS_PAD  (K_KNOTS + 8)

typedef float vfloat4 __attribute__((ext_vector_type(4)));   // nontemporal-safe

struct __align__(8) TabE { float t1; unsigned int s0; };     // one ds_read_b64

// ---------------------------------------------------------------------------
// Session findings (rounds 0-6), recorded for posterity:
//  * dur_us = harness fills (3 x 41us = 123us, 256MiB re-poisons, HBM-bound
//    at 6.5 TB/s) + non-overlapped tail of our chain. Fills OVERLAP our
//    kernels; eval runs concurrent with fills and is HBM-CONTENTION-bound
//    (same kernel measured at 1.57-2.42 TB/s across passes).
//  * eval duration is invariant (~42us) across: 5 vs 3 gathers/pt, batched
//    vs divergent resolution, 16 vs 32 waves/CU, LDS vs L1 tab, x-prefetch.
//    Internal structure is NOT the limiter; do not touch.
//  * sort as 1 wave/block cost ~20us serial (round-2 fix: 4-way split = R3's
//    -23us win). Cooperative sort+prep fusion REGRESSED +26us (cooperative
//    launch is graph-capture-hostile here). Prep fused into eval prologue
//    REGRESSED +5us (redundant per-block work x1024 blocks).
//  * This exact configuration measured 137.2us (session best).
// ---------------------------------------------------------------------------

// ---------------------------------------------------------------------------
// Kernel 1: rank sort of the 1024 knots (stable, tie-safe).
// 16 blocks x 256: block owns 64 elements; wave q (=tid>>6) scans knot
// quarter q for all 64 elements -> partial ranks; 4-way LDS reduction.
// ---------------------------------------------------------------------------
__global__ __launch_bounds__(256) void sort_knots_kernel(
        const float* __restrict__ knots, float* __restrict__ ts) {
    __shared__ __align__(16) float kl[K_KNOTS];
    __shared__ int part[4][64];
    const int tid  = threadIdx.x;
    const int lane = tid & 63;          // element slot within the block
    const int q    = tid >> 6;          // knot quarter (uniform per wave)
    const int e    = blockIdx.x * 64 + lane;   // global element index

    ((float4*)kl)[tid] = ((const float4*)knots)[tid];   // 256 x float4 = 1024
    __syncthreads();

    const float my = kl[e];
    int rank = 0;
    const float4* kl4 = (const float4*)kl;
    const int j4lo = q * (K_KNOTS / 16);       // 64 float4 per quarter
#pragma unroll 8
    for (int j4 = j4lo; j4 < j4lo + K_KNOTS / 16; ++j4) {
        const float4 v = kl4[j4];              // broadcast (uniform per wave)
        const int j = j4 * 4;
        rank += (v.x < my || (v.x == my && j + 0 < e)) ? 1 : 0;
        rank += (v.y < my || (v.y == my && j + 1 < e)) ? 1 : 0;
        rank += (v.z < my || (v.z == my && j + 2 < e)) ? 1 : 0;
        rank += (v.w < my || (v.w == my && j + 3 < e)) ? 1 : 0;
    }
    part[q][lane] = rank;
    __syncthreads();
    if (q == 0) {
        const int r = part[0][lane] + part[1][lane] + part[2][lane] + part[3][lane];
        ts[r] = my;
    }
}

// ---------------------------------------------------------------------------
// Cubic in u = x - tref carried through the de Boor recursion (prep only,
// double precision to kill cancellation for tiny knot gaps).
// ---------------------------------------------------------------------------
struct PolyD { double c0, c1, c2, c3; };

__device__ __forceinline__ PolyD lerp_poly(const PolyD dl, const PolyD dr,
                                           double tl, double tr, double tref) {
    const double inv = 1.0 / (tr - tl);
    const double A = (tref - tl) * inv;
    const double e0 = dr.c0 - dl.c0, e1 = dr.c1 - dl.c1;
    const double e2 = dr.c2 - dl.c2, e3 = dr.c3 - dl.c3;
    PolyD o;
    o.c0 = dl.c0 + A * e0;
    o.c1 = dl.c1 + A * e1 + inv * e0;
    o.c2 = dl.c2 + A * e2 + inv * e1;
    o.c3 = dl.c3 + A * e3 + inv * e2;
    return o;
}

// cubic for interval s (ts[s-1] < x <= ts[s], s in [4,1020]) centered at tref
__device__ __forceinline__ float4 interval_poly(const float* tss,
                                                const float* __restrict__ c,
                                                int s, double tref) {
    const double T0 = tss[s - 3], T1 = tss[s - 2], T2 = tss[s - 1];
    const double T3 = tss[s],     T4 = tss[s + 1], T5 = tss[s + 2];
    PolyD d0 = {(double)c[s - 4], 0, 0, 0}, d1 = {(double)c[s - 3], 0, 0, 0};
    PolyD d2 = {(double)c[s - 2], 0, 0, 0}, d3 = {(double)c[s - 1], 0, 0, 0};
    d3 = lerp_poly(d2, d3, T2, T5, tref);   // r=1
    d2 = lerp_poly(d1, d2, T1, T4, tref);
    d1 = lerp_poly(d0, d1, T0, T3, tref);
    d3 = lerp_poly(d2, d3, T2, T4, tref);   // r=2
    d2 = lerp_poly(d1, d2, T1, T3, tref);
    d3 = lerp_poly(d2, d3, T2, T3, tref);   // r=3
    return make_float4((float)d3.c0, (float)d3.c1, (float)d3.c2, (float)d3.c3);
}

// ---------------------------------------------------------------------------
// Kernel 2 (prep), 12 blocks x 256:
//  threads 0..1023    -> coef[s]: interval cubic centered at gm = m/MGRID,
//                        m = round(ts[s]*MGRID); m packed into the low 13
//                        mantissa bits of c3 (<=2^-10 rel perturbation).
//  threads 1024..3071 -> tab[b] = {t1 = ts[s0], s0} where s0 = clamp(
//                        lower_bound(ts, Lb-eps), 4, 1020). First scan
//                        iteration precomputed; eval does s = s0 + (t1<x),
//                        then a check read + rare scan.
// ---------------------------------------------------------------------------
__device__ __forceinline__ int lower_bound_s(const float* tss, float v) {
    int lo = 0, hi = K_KNOTS;
    while (lo < hi) {
        const int mid = (lo + hi) >> 1;
        if (tss[mid] < v) lo = mid + 1; else hi = mid;
    }
    return lo;
}

__global__ void prep_kernel(const float* __restrict__ ts,
                            const float* __restrict__ c,
                            float4* __restrict__ coefI,
                            TabE* __restrict__ tab) {
    __shared__ float tss[K_KNOTS];
    const int tid = threadIdx.x;
    for (int i = tid; i < K_KNOTS; i += blockDim.x) tss[i] = ts[i];
    __syncthreads();

    const int g = blockIdx.x * blockDim.x + tid;   // 0..3071
    if (g < K_KNOTS) {
        const int s = g;
        float4 out = make_float4(0.f, 0.f, 0.f, 0.f);
        if (s >= 4 && s <= 1020) {
            int m = (int)((double)tss[s] * (double)MGRID + 0.5);
            m = m < 0 ? 0 : (m > MGRID ? MGRID : m);         // fits 13 bits
            const double gm = (double)m * (1.0 / (double)MGRID);
            float4 p = interval_poly(tss, c, s, gm);
            const unsigned int wb =
                (__float_as_uint(p.w) & ~0x1FFFu) | (unsigned int)m;
            p.w = __uint_as_float(wb);
            out = p;
        }
        coefI[s] = out;
    } else {
        const int b = g - K_KNOTS;                 // 0..2047
        const float eps = 1e-6f;                   // >> 6e-8 edge-rounding slack
        const float Lb = (float)b * (1.0f / (float)TABM) - eps;
        int s0 = lower_bound_s(tss, Lb);
        // clamp: domain guarantees true s in [4,1020] and s0 <= true s, so
        // clamping keeps s0 <= true s for every queried bucket (scan fixes up)
        s0 = s0 < 4 ? 4 : (s0 > 1020 ? 1020 : s0);
        TabE e; e.t1 = tss[s0]; e.s0 = (unsigned int)s0;
        tab[b] = e;
    }
}

// ---------------------------------------------------------------------------
// Kernel 3: evaluation. 3 LDS gathers/point:
//   P1: {t1,s0} = tab[b]        (8x ds_read_b64)  -- fuses lookup + probe 1
//   P2: s = s0 + (t1 < x); t = ts[s]  (8x ds_read_b32, loop-entry check)
//   P3: rare residual scan      (P(lane) ~3.2%, sparse, exact)
//   P4: e = coef[s]             (8x ds_read_b128) + Horner
// HBM-contention-bound vs the concurrent harness fills — internal structure
// verified irrelevant (rounds 0-6). 36 KB LDS -> 4 blk/CU.
// ---------------------------------------------------------------------------
__global__ __launch_bounds__(256, 4) void eval_kernel(
        const vfloat4* __restrict__ x4,
        const float* __restrict__ ts_g,
        const float4* __restrict__ coefI_g,
        const TabE* __restrict__ tab_g,
        vfloat4* __restrict__ out4, int n4) {
    __shared__ __align__(16) TabE   tab_s[TABM];      // 16 KB
    __shared__ __align__(16) float4 coefI_s[K_KNOTS]; // 16 KB
    __shared__ __align__(16) float  ts_s[TS_PAD];     // ~4 KB (36 KB tot)
    const int tid = threadIdx.x;

#pragma unroll
    for (int i = tid; i < (TABM * 8) / 16; i += 256)  // 1024 uint4
        ((uint4*)tab_s)[i] = ((const uint4*)tab_g)[i];
#pragma unroll
    for (int i = tid; i < K_KNOTS; i += 256) coefI_s[i] = coefI_g[i];
    for (int i = tid; i < TS_PAD; i += 256)
        ts_s[i] = (i < K_KNOTS) ? ts_g[i] : 1e30f;    // pad bounds the scan
    __syncthreads();

    const int gid    = blockIdx.x * 256 + tid;
    const int stride = gridDim.x * 256;
    for (int i = gid; i < n4; i += 2 * stride) {
        const int i2 = i + stride;
        const bool has2 = i2 < n4;
        const vfloat4 xa = __builtin_nontemporal_load(&x4[i]);
        const vfloat4 xb = has2 ? __builtin_nontemporal_load(&x4[i2]) : xa;
        float xx[8] = {xa.x, xa.y, xa.z, xa.w, xb.x, xb.y, xb.z, xb.w};

        // P1: fused table+probe1 (8 independent ds_read_b64)
        TabE eb[8];
#pragma unroll
        for (int j = 0; j < 8; ++j) {
            const int b = (int)(xx[j] * (float)TABM);
            eb[j] = tab_s[b];
        }
        // P2: increment + loop-entry check read (8 independent ds_read_b32)
        int ss[8];
#pragma unroll
        for (int j = 0; j < 8; ++j)
            ss[j] = (int)eb[j].s0 + ((eb[j].t1 < xx[j]) ? 1 : 0);
        float tt[8];
#pragma unroll
        for (int j = 0; j < 8; ++j) tt[j] = ts_s[ss[j]];
        // P3: rare residual scan (exact lower bound from any start <= true s)
#pragma unroll
        for (int j = 0; j < 8; ++j) {
            while (tt[j] < xx[j]) { ++ss[j]; tt[j] = ts_s[ss[j]]; }
        }
        // P4: coefficient fetch (8 independent ds_read_b128) + Horner
        float4 ee[8];
#pragma unroll
        for (int j = 0; j < 8; ++j) ee[j] = coefI_s[ss[j]];
        float rr[8];
#pragma unroll
        for (int j = 0; j < 8; ++j) {
            const float4 e = ee[j];
            const int m = (int)(__float_as_uint(e.w) & 0x1FFFu);
            const float u = __builtin_fmaf((float)m, -1.0f / (float)MGRID, xx[j]);
            rr[j] = e.x + u * (e.y + u * (e.z + u * e.w));
        }
        vfloat4 ra, rb;
        ra.x = rr[0]; ra.y = rr[1]; ra.z = rr[2]; ra.w = rr[3];
        rb.x = rr[4]; rb.y = rr[5]; rb.z = rr[6]; rb.w = rr[7];
        __builtin_nontemporal_store(ra, &out4[i]);
        if (has2) __builtin_nontemporal_store(rb, &out4[i2]);
    }
}

extern "C" void kernel_launch(void* const* d_in, const int* in_sizes, int n_in,
                              void* d_out, int out_size, void* d_ws, size_t ws_size,
                              hipStream_t stream) {
    const float* x     = (const float*)d_in[0];  // [16777216]
    const float* knots = (const float*)d_in[1];  // [1024] unsorted
    const float* c     = (const float*)d_in[2];  // [1021]
    float* out = (float*)d_out;

    // ws layout: ts @0 (4 KB) | coefI @4K (16 KB) | tab @20K (16 KB)
    float*  ts_ws    = (float*)d_ws;
    float4* coefI_ws = (float4*)((char*)d_ws + 4096);
    TabE*   tab_ws   = (TabE*)((char*)d_ws + 4096 + 16384);

    sort_knots_kernel<<<16, 256, 0, stream>>>(knots, ts_ws);
    prep_kernel<<<(K_KNOTS + TABM) / 256, 256, 0, stream>>>(ts_ws, c, coefI_ws, tab_ws);

    const int n4 = out_size / 4;   // 4,194,304
    // 1024 blocks = 4 resident blocks/CU x 256 CUs (36 KB LDS -> 4 blocks/CU)
    eval_kernel<<<1024, 256, 0, stream>>>((const vfloat4*)x, ts_ws, coefI_ws,
                                          tab_ws, (vfloat4*)out, n4);
}